// Round 7
// baseline (182.683 us; speedup 1.0000x reference)
//
#include <hip/hip_runtime.h>
#include <stdint.h>

// Problem constants (fixed shapes from reference)
#define M_ROWS 6272   // 32*196
#define K_DIM  768
#define N_DIM  3072
#define BM 128
#define BN 128
#define BK 32
#define NITER (K_DIM / BK)   // 24

#define X_CHUNKS (M_ROWS * K_DIM / 8)   // 602112
#define W_CHUNKS (N_DIM * K_DIM / 8)    // 294912
#define X_BLOCKS (X_CHUNKS / 256)       // 2352
#define W_BLOCKS (W_CHUNKS / 256)       // 1152

typedef unsigned short u16;
typedef __attribute__((ext_vector_type(8))) __bf16 bf16x8;
typedef __attribute__((ext_vector_type(4))) float f32x4;

__device__ __forceinline__ u16 f32_to_bf16(float f) {
    unsigned u = __float_as_uint(f);
    unsigned r = 0x7FFFu + ((u >> 16) & 1u);
    return (u16)((u + r) >> 16);
}

__device__ __forceinline__ unsigned pack2(float a, float b) {
    return (unsigned)f32_to_bf16(a) | ((unsigned)f32_to_bf16(b) << 16);
}

// LDS-only barrier: drains lgkmcnt but NOT vmcnt (R4, verified correct).
__device__ __forceinline__ void lds_barrier() {
    asm volatile("s_waitcnt lgkmcnt(0)\n\ts_barrier" ::: "memory");
}

// Fused prep: blocks [0, X_BLOCKS) cast x fp32->bf16;
// blocks [X_BLOCKS, X_BLOCKS+W_BLOCKS) expand block-circulant W to bf16.
__global__ void prep_kernel(const float* __restrict__ x, const float* __restrict__ w,
                            u16* __restrict__ xb, u16* __restrict__ wb) {
    int b = blockIdx.x;
    if (b < X_BLOCKS) {
        int idx = b * 256 + threadIdx.x;
        const float4* xp = (const float4*)x + (size_t)idx * 2;
        float4 a = xp[0], c = xp[1];
        uint4 v;
        v.x = pack2(a.x, a.y);
        v.y = pack2(a.z, a.w);
        v.z = pack2(c.x, c.y);
        v.w = pack2(c.z, c.w);
        ((uint4*)xb)[idx] = v;
    } else {
        int idx = (b - X_BLOCKS) * 256 + threadIdx.x;
        int n    = idx / 96;          // output row [0,3072)
        int kc   = idx - n * 96;      // 8-elem chunk along K
        int kblk = n / 768;           // 0..3
        int o    = n - kblk * 768;    // 0..767
        int j    = kc / 24;           // 0..3
        int c8   = kc - j * 24;       // 0..23
        int i    = (kblk - j) & 3;    // (kblk - j) mod 4
        const float* src = w + (((size_t)i * 768 + o) * 192 + c8 * 8);
        float4 a = ((const float4*)src)[0];
        float4 c = ((const float4*)src)[1];
        uint4 v;
        v.x = pack2(a.x, a.y);
        v.y = pack2(a.z, a.w);
        v.z = pack2(c.x, c.y);
        v.w = pack2(c.z, c.w);
        ((uint4*)wb)[idx] = v;
    }
}

// C[m,n] = sum_k A[m,k]*B[n,k] + bias[n]; A,B bf16 row-major K-contig, C fp32.
//
// R7: 4-stage LDS pipeline. R3's 50us plateau = per-iter ds_read->MFMA
// latency exposed serially 24 times (nothing >35% busy). Here, per iter t:
//   1. issue frag ds_reads for tile t+1 (LDS-staged in iter t-1, visible)
//   2. ds_write tile t+2 from regs (globally loaded in iter t-1)
//   3. global loads tile t+3 -> regs
//   4. MFMA tile t  -- operands were ds_read a FULL ITERATION ago
//   5. lgkm-only barrier
// Every consumer has >=1 iteration of latency slack. 4 LDS buffers (64 KB,
// 2 blocks/CU — matches the VGPR-implied occupancy, so no loss). Register
// WAR on the 2-set rotations caps loads in flight (no hoisting blowup).
// LDS XOR swizzle (R2, verified, conflicts=0) retained.
__global__ __launch_bounds__(256) void gemm_bt(
    const u16* __restrict__ A,    // [M_ROWS, K_DIM] bf16
    const u16* __restrict__ B,    // [N_DIM,  K_DIM] bf16
    const float* __restrict__ bias,
    float* __restrict__ C)
{
    __shared__ u16 As[4][BM * BK];   // 4 x 8 KB
    __shared__ u16 Bs[4][BN * BK];   // 4 x 8 KB   (total 64 KB)

    const int tid    = threadIdx.x;
    const int wave   = tid >> 6;
    const int lane   = tid & 63;
    const int lane16 = lane & 15;
    const int quad   = lane >> 4;
    const int wr     = wave >> 1;   // 0..1
    const int wc     = wave & 1;    // 0..1

    const int rowBase = blockIdx.y * BM;
    const int colBase = blockIdx.x * BN;

    // staging: chunk c in [0,512): row = c>>2, lds slot = c&3,
    // global k-slot = (c&3) ^ ((row>>1)&3). 2 A + 2 B chunks per thread.
    const int c0 = tid;
    const int c1 = tid + 256;
    const int r0 = c0 >> 2, s0 = (c0 & 3) ^ ((r0 >> 1) & 3);
    const int r1 = c1 >> 2, s1 = (c1 & 3) ^ ((r1 >> 1) & 3);
    const uint4* Ag0 = (const uint4*)(A + (size_t)(rowBase + r0) * K_DIM + s0 * 8);
    const uint4* Ag1 = (const uint4*)(A + (size_t)(rowBase + r1) * K_DIM + s1 * 8);
    const uint4* Bg0 = (const uint4*)(B + (size_t)(colBase + r0) * K_DIM + s0 * 8);
    const uint4* Bg1 = (const uint4*)(B + (size_t)(colBase + r1) * K_DIM + s1 * 8);
    const int l0 = c0 * 8;   // element offset within a buffer
    const int l1 = c1 * 8;
    const int kStep = BK / 8;   // uint4 per K-tile advance per row

    // read-side swizzle
    const int swz  = (lane16 >> 1) & 3;
    const int slot = (quad ^ swz) * 8;
    int aoff[4], boff[4];
#pragma unroll
    for (int i = 0; i < 4; ++i)
        aoff[i] = (wr * 64 + i * 16 + lane16) * BK + slot;
#pragma unroll
    for (int j = 0; j < 4; ++j)
        boff[j] = (wc * 64 + j * 16 + lane16) * BK + slot;

    f32x4 acc[4][4] = {};

    uint4 gA0[2], gA1[2], gB0[2], gB1[2];   // global staging, tile m -> set m&1
    bf16x8 afr[2][4], bfr[2][4];            // fragments,      tile m -> set m&1

    // ---- prologue ----
    // tile0 -> regs set0 -> buf0
    gA0[0] = Ag0[0]; gA1[0] = Ag1[0]; gB0[0] = Bg0[0]; gB1[0] = Bg1[0];
    *(uint4*)&As[0][l0] = gA0[0]; *(uint4*)&As[0][l1] = gA1[0];
    *(uint4*)&Bs[0][l0] = gB0[0]; *(uint4*)&Bs[0][l1] = gB1[0];
    // tile1 -> regs set1 -> buf1
    gA0[1] = Ag0[kStep]; gA1[1] = Ag1[kStep]; gB0[1] = Bg0[kStep]; gB1[1] = Bg1[kStep];
    *(uint4*)&As[1][l0] = gA0[1]; *(uint4*)&As[1][l1] = gA1[1];
    *(uint4*)&Bs[1][l0] = gB0[1]; *(uint4*)&Bs[1][l1] = gB1[1];
    // tile2 -> regs set0
    gA0[0] = Ag0[2 * kStep]; gA1[0] = Ag1[2 * kStep];
    gB0[0] = Bg0[2 * kStep]; gB1[0] = Bg1[2 * kStep];
    lds_barrier();   // tiles 0,1 visible
    // frags tile0 -> set0
#pragma unroll
    for (int i = 0; i < 4; ++i) afr[0][i] = *(const bf16x8*)&As[0][aoff[i]];
#pragma unroll
    for (int j = 0; j < 4; ++j) bfr[0][j] = *(const bf16x8*)&Bs[0][boff[j]];

    // ---- main loop: t = 0 .. NITER-4 (= 20) ----
#pragma unroll
    for (int t = 0; t < NITER - 3; ++t) {
        const int s  = t & 1, sn = s ^ 1;
        const int bN = (t + 1) & 3;   // buffer holding tile t+1
        const int bW = (t + 2) & 3;   // buffer to write tile t+2

        // 1. frag reads tile t+1 -> set sn (consumed next iter)
#pragma unroll
        for (int i = 0; i < 4; ++i) afr[sn][i] = *(const bf16x8*)&As[bN][aoff[i]];
#pragma unroll
        for (int j = 0; j < 4; ++j) bfr[sn][j] = *(const bf16x8*)&Bs[bN][boff[j]];

        // 2. ds_write tile t+2 from regs set s ((t+2)&1 == s)
        *(uint4*)&As[bW][l0] = gA0[s]; *(uint4*)&As[bW][l1] = gA1[s];
        *(uint4*)&Bs[bW][l0] = gB0[s]; *(uint4*)&Bs[bW][l1] = gB1[s];

        // 3. global loads tile t+3 -> regs set sn
        {
            const int g = (t + 3) * kStep;
            gA0[sn] = Ag0[g]; gA1[sn] = Ag1[g];
            gB0[sn] = Bg0[g]; gB1[sn] = Bg1[g];
        }

        // 4. MFMA tile t (operands read one full iteration ago)
#pragma unroll
        for (int i = 0; i < 4; ++i)
#pragma unroll
            for (int j = 0; j < 4; ++j)
                acc[i][j] = __builtin_amdgcn_mfma_f32_16x16x32_bf16(
                    afr[s][i], bfr[s][j], acc[i][j], 0, 0, 0);

        lds_barrier();
    }

    // t = 21 (s=1): frag reads tile22 -> set0; ds_write tile23; MFMA set1
    {
#pragma unroll
        for (int i = 0; i < 4; ++i) afr[0][i] = *(const bf16x8*)&As[22 & 3][aoff[i]];
#pragma unroll
        for (int j = 0; j < 4; ++j) bfr[0][j] = *(const bf16x8*)&Bs[22 & 3][boff[j]];
        *(uint4*)&As[23 & 3][l0] = gA0[1]; *(uint4*)&As[23 & 3][l1] = gA1[1];
        *(uint4*)&Bs[23 & 3][l0] = gB0[1]; *(uint4*)&Bs[23 & 3][l1] = gB1[1];
#pragma unroll
        for (int i = 0; i < 4; ++i)
#pragma unroll
            for (int j = 0; j < 4; ++j)
                acc[i][j] = __builtin_amdgcn_mfma_f32_16x16x32_bf16(
                    afr[1][i], bfr[1][j], acc[i][j], 0, 0, 0);
        lds_barrier();
    }

    // t = 22 (s=0): frag reads tile23 -> set1; MFMA set0
    {
#pragma unroll
        for (int i = 0; i < 4; ++i) afr[1][i] = *(const bf16x8*)&As[23 & 3][aoff[i]];
#pragma unroll
        for (int j = 0; j < 4; ++j) bfr[1][j] = *(const bf16x8*)&Bs[23 & 3][boff[j]];
#pragma unroll
        for (int i = 0; i < 4; ++i)
#pragma unroll
            for (int j = 0; j < 4; ++j)
                acc[i][j] = __builtin_amdgcn_mfma_f32_16x16x32_bf16(
                    afr[0][i], bfr[0][j], acc[i][j], 0, 0, 0);
    }

    // t = 23: MFMA set1
    {
#pragma unroll
        for (int i = 0; i < 4; ++i)
#pragma unroll
            for (int j = 0; j < 4; ++j)
                acc[i][j] = __builtin_amdgcn_mfma_f32_16x16x32_bf16(
                    afr[1][i], bfr[1][j], acc[i][j], 0, 0, 0);
    }

    // epilogue: C[row][col] = acc + bias[col]
    float bv[4];
#pragma unroll
    for (int j = 0; j < 4; ++j)
        bv[j] = bias[colBase + wc * 64 + j * 16 + lane16];
#pragma unroll
    for (int i = 0; i < 4; ++i) {
        int row0 = rowBase + wr * 64 + i * 16 + quad * 4;
#pragma unroll
        for (int r = 0; r < 4; ++r) {
            float* cp = C + (size_t)(row0 + r) * N_DIM + colBase + wc * 64 + lane16;
#pragma unroll
            for (int j = 0; j < 4; ++j)
                cp[j * 16] = acc[i][j][r] + bv[j];
        }
    }
}

extern "C" void kernel_launch(void* const* d_in, const int* in_sizes, int n_in,
                              void* d_out, int out_size, void* d_ws, size_t ws_size,
                              hipStream_t stream) {
    const float* x    = (const float*)d_in[0];
    const float* w    = (const float*)d_in[1];
    const float* bias = (const float*)d_in[2];
    float* out = (float*)d_out;

    u16* xb = (u16*)d_ws;                                       // 9,633,792 B
    u16* wb = (u16*)((char*)d_ws + (size_t)M_ROWS * K_DIM * 2); // +4,718,592 B

    hipLaunchKernelGGL(prep_kernel, dim3(X_BLOCKS + W_BLOCKS), dim3(256),
                       0, stream, x, w, xb, wb);
    hipLaunchKernelGGL(gemm_bt, dim3(N_DIM / BN, M_ROWS / BM), dim3(256),
                       0, stream, xb, wb, bias, out);
}